// Round 9
// baseline (401.474 us; speedup 1.0000x reference)
//
#include <hip/hip_runtime.h>
#include <hip/hip_bf16.h>

typedef __attribute__((ext_vector_type(8))) short bf16x8;
typedef __attribute__((ext_vector_type(4))) float f32x4;

#define SEQ 2048
#define DM  512
#define NH  8
#define DH  64
// (1/sqrt(2048)) * log2(e): folded into Q so scores come out ready for exp2
#define QSCALE 0.031879360f

__device__ __forceinline__ unsigned short f2bf(float f) {
  unsigned int u = __float_as_uint(f);
  unsigned int r = 0x7FFFu + ((u >> 16) & 1u);
  return (unsigned short)((u + r) >> 16);
}

__device__ __forceinline__ void load8f(const float* __restrict__ s,
                                       unsigned short* __restrict__ o) {
  float4 v0 = *(const float4*)s;
  float4 v1 = *(const float4*)(s + 4);
  o[0] = f2bf(v0.x); o[1] = f2bf(v0.y); o[2] = f2bf(v0.z); o[3] = f2bf(v0.w);
  o[4] = f2bf(v1.x); o[5] = f2bf(v1.y); o[6] = f2bf(v1.z); o[7] = f2bf(v1.w);
}

// ---------- fused weight prep: Wq/Wk/Wv per-head transpose + Wo transpose (f32->bf16) ----------
__global__ __launch_bounds__(256) void weight_prep(const float* __restrict__ Wq,
                                                   const float* __restrict__ Wk,
                                                   const float* __restrict__ Wv,
                                                   const float* __restrict__ Wo,
                                                   unsigned short* __restrict__ Wqt,
                                                   unsigned short* __restrict__ Wkt,
                                                   unsigned short* __restrict__ Wvt,
                                                   unsigned short* __restrict__ Wot) {
  const int which = blockIdx.x >> 6, wi = blockIdx.x & 63;
  const float* src;
  unsigned short* dst;
  int R, C, r0, c0;
  if (which < 3) {
    const float* W = (which == 0) ? Wq : (which == 1) ? Wk : Wv;
    unsigned short* D = (which == 0) ? Wqt : (which == 1) ? Wkt : Wvt;
    int h = wi >> 3;
    src = W + (size_t)h * 512 * 64;
    dst = D + (size_t)h * 64 * 512;
    R = 512; C = 64; r0 = (wi & 7) * 64; c0 = 0;
  } else {
    src = Wo; dst = Wot;
    R = 512; C = 512; r0 = (wi >> 3) * 64; c0 = (wi & 7) * 64;
  }
  __shared__ __align__(16) unsigned short T[64][72];
  const int tid = threadIdx.x;
#pragma unroll
  for (int i = 0; i < 2; ++i) {
    int c = tid + 256 * i;
    int lr = c >> 3, lc = (c & 7) * 8;
    __align__(16) unsigned short tmp[8];
    load8f(src + (size_t)(r0 + lr) * C + c0 + lc, tmp);
    *(uint4*)&T[lr][lc] = *(const uint4*)tmp;
  }
  __syncthreads();
#pragma unroll
  for (int i = 0; i < 2; ++i) {
    int c = tid + 256 * i;
    int orow = c >> 3, och = (c & 7) * 8;
    __align__(16) unsigned short tmp[8];
#pragma unroll
    for (int j = 0; j < 8; ++j) tmp[j] = T[och + j][orow];
    *(uint4*)(dst + (size_t)(c0 + orow) * R + r0 + och) = *(uint4*)tmp;
  }
}

// ---------- fused QKV projection, 128x128 tiles ----------
__global__ __launch_bounds__(256, 4) void proj128(const float* __restrict__ q,
                                                  const float* __restrict__ k,
                                                  const float* __restrict__ v,
                                                  const unsigned short* __restrict__ Wqt,
                                                  const unsigned short* __restrict__ Wkt,
                                                  const unsigned short* __restrict__ Wvt,
                                                  const float* __restrict__ bq,
                                                  const float* __restrict__ bk,
                                                  const float* __restrict__ bv,
                                                  unsigned short* __restrict__ Qp,
                                                  unsigned short* __restrict__ Kp,
                                                  unsigned short* __restrict__ Vpt) {
  const int which = blockIdx.z;
  const float* X = (which == 0) ? q : (which == 1) ? k : v;
  const unsigned short* Wt = (which == 0) ? Wqt : (which == 1) ? Wkt : Wvt;
  const float* bias = (which == 0) ? bq : (which == 1) ? bk : bv;
  unsigned short* out = (which == 0) ? Qp : (which == 1) ? Kp : Vpt;
  const float ps = (which == 0) ? QSCALE : 1.0f;

  const int m0 = blockIdx.x * 128;
  const int n0 = blockIdx.y * 128;
  __shared__ __align__(16) unsigned short smem[2][128][72];
  unsigned short (*As)[72] = smem[0];
  unsigned short (*Bs)[72] = smem[1];
  const int tid  = threadIdx.x;
  const int wave = tid >> 6, lane = tid & 63;
  const int l15  = lane & 15, quad = lane >> 4;
  const int rb = (wave >> 1) * 64, cb = (wave & 1) * 64;

  f32x4 acc[4][4];
#pragma unroll
  for (int i = 0; i < 4; ++i)
#pragma unroll
    for (int f = 0; f < 4; ++f) acc[i][f] = (f32x4){0.f, 0.f, 0.f, 0.f};

  for (int k0 = 0; k0 < DM; k0 += 64) {
    __syncthreads();
#pragma unroll
    for (int i = 0; i < 4; ++i) {
      int c = tid + 256 * i;
      int lr = c >> 3, lc = (c & 7) * 8;
      __align__(16) unsigned short tmp[8];
      load8f(X + (size_t)(m0 + lr) * DM + k0 + lc, tmp);
      *(uint4*)&As[lr][lc] = *(const uint4*)tmp;
      *(uint4*)&Bs[lr][lc] = *(const uint4*)(Wt + (size_t)(n0 + lr) * DM + k0 + lc);
    }
    __syncthreads();
#pragma unroll
    for (int kc = 0; kc < 2; ++kc) {
      bf16x8 av[4], bv4[4];
#pragma unroll
      for (int i = 0; i < 4; ++i) av[i]  = *(const bf16x8*)&As[rb + 16 * i + l15][kc * 32 + quad * 8];
#pragma unroll
      for (int f = 0; f < 4; ++f) bv4[f] = *(const bf16x8*)&Bs[cb + 16 * f + l15][kc * 32 + quad * 8];
#pragma unroll
      for (int i = 0; i < 4; ++i)
#pragma unroll
        for (int f = 0; f < 4; ++f)
          acc[i][f] = __builtin_amdgcn_mfma_f32_16x16x32_bf16(av[i], bv4[f], acc[i][f], 0, 0, 0);
    }
  }

  if (which < 2) {
#pragma unroll
    for (int i = 0; i < 4; ++i)
#pragma unroll
      for (int f = 0; f < 4; ++f)
#pragma unroll
        for (int r = 0; r < 4; ++r) {
          int m = m0 + rb + 16 * i + quad * 4 + r;
          int col = n0 + cb + 16 * f + l15;
          int head = col >> 6, o = col & 63;
          int b = m >> 11, s = m & (SEQ - 1);
          float val = (acc[i][f][r] + bias[col]) * ps;
          out[(((size_t)(b * NH + head) * SEQ + s) << 6) + o] = f2bf(val);
        }
  } else {  // V: emit V^T [B,H,64,S] via per-wave LDS bounce transpose
    __syncthreads();
    unsigned short* T = &smem[0][0][0] + wave * 4608;  // [64][72] per wave
#pragma unroll
    for (int i = 0; i < 4; ++i)
#pragma unroll
      for (int f = 0; f < 4; ++f)
#pragma unroll
        for (int r = 0; r < 4; ++r) {
          int lrow = 16 * i + quad * 4 + r;
          int lcol = 16 * f + l15;
          int col = n0 + cb + 16 * f + l15;
          T[lcol * 72 + lrow] = f2bf(acc[i][f][r] + bias[col]);
        }
    const int mbase = m0 + rb;
    const int b = mbase >> 11, sbase = mbase & (SEQ - 1);
    const int head = (n0 + cb) >> 6;
    unsigned short* dstb = out + ((size_t)(b * NH + head) * DH) * SEQ + sbase;
#pragma unroll
    for (int j = 0; j < 8; ++j) {
      int dh = (lane >> 3) + j * 8;
      int sc = (lane & 7) * 8;
      *(uint4*)(dstb + (size_t)dh * SEQ + sc) = *(const uint4*)&T[dh * 72 + sc];
    }
  }
}

// ---------- flash attention v4: NO barriers. K/V fragments direct global->register ----------
// Per-bh K+V (512 KB) is L2-resident; 4 waves/block read identical chunks -> L1 reuse.
// Only Ps (wave-private rows) lives in LDS. Qp pre-scaled. grid (32 qt big-first, 32 bh).
__global__ __launch_bounds__(256) void attn_kernel(const unsigned short* __restrict__ Qp,
                                                   const unsigned short* __restrict__ Kp,
                                                   const unsigned short* __restrict__ Vpt,
                                                   unsigned short* __restrict__ concat) {
  const int qt = 31 - blockIdx.x;   // big blocks dispatched first
  const int bh = blockIdx.y;
  const int b = bh >> 3, h = bh & 7;
  __shared__ __align__(16) unsigned short Ps[64][136];   // wave-private 16-row bands
  const int tid  = threadIdx.x;
  const int wave = tid >> 6, lane = tid & 63;
  const int l15  = lane & 15, quad = lane >> 4;
  const unsigned short* Qb = Qp  + (size_t)bh * SEQ * DH;
  const unsigned short* Kb = Kp  + (size_t)bh * SEQ * DH;
  const unsigned short* Vb = Vpt + (size_t)bh * DH * SEQ;
  const int q0 = qt * 64;

  // Q fragments: rows q0 + 16*wave + l15, k-cols quad*8 (+32 for kc=1)
  bf16x8 aq[2];
#pragma unroll
  for (int kc = 0; kc < 2; ++kc)
    aq[kc] = *(const bf16x8*)(Qb + (size_t)(q0 + 16 * wave + l15) * DH + kc * 32 + quad * 8);

  float l_lane[4];
  f32x4 Of[4];
#pragma unroll
  for (int r = 0; r < 4; ++r) l_lane[r] = 0.f;
#pragma unroll
  for (int f = 0; f < 4; ++f) Of[f] = (f32x4){0.f, 0.f, 0.f, 0.f};

  // per-lane base pointers for K/V fragment streams
  const unsigned short* kbase = Kb + (size_t)(16 * 0 + l15) * DH + quad * 8;  // + f*16*DH + kc*32 + l0*DH
  const unsigned short* vbase = Vb + (size_t)l15 * SEQ + quad * 8;            // + f*16*SEQ + kc*32 + l0

#pragma unroll 1
  for (int ch = 0; ch <= qt; ++ch) {
    const int l0 = ch * 64;

    // K fragments: B-operand n = l0+16f+l15 (key), k = kc*32+quad*8+j (dh)
    bf16x8 kf[2][4], vf[2][4];
#pragma unroll
    for (int kc = 0; kc < 2; ++kc)
#pragma unroll
      for (int f = 0; f < 4; ++f)
        kf[kc][f] = *(const bf16x8*)(kbase + (size_t)(l0 + 16 * f) * DH + kc * 32);
    // V fragments: B-operand n = 16f+l15 (dh), k = kc*32+quad*8+j (key-local)
#pragma unroll
    for (int kc = 0; kc < 2; ++kc)
#pragma unroll
      for (int f = 0; f < 4; ++f)
        vf[kc][f] = *(const bf16x8*)(vbase + (size_t)(16 * f) * SEQ + l0 + kc * 32);

    // S' = Q K^T (scores pre-multiplied by scale*log2e via Q)
    f32x4 S[4];
#pragma unroll
    for (int f = 0; f < 4; ++f) S[f] = (f32x4){0.f, 0.f, 0.f, 0.f};
#pragma unroll
    for (int kc = 0; kc < 2; ++kc)
#pragma unroll
      for (int f = 0; f < 4; ++f)
        S[f] = __builtin_amdgcn_mfma_f32_16x16x32_bf16(aq[kc], kf[kc][f], S[f], 0, 0, 0);

    if (ch == qt) {  // diagonal tile: causal mask
      const int mrow = q0 + 16 * wave + quad * 4;
#pragma unroll
      for (int f = 0; f < 4; ++f)
#pragma unroll
        for (int r = 0; r < 4; ++r)
          if (l0 + 16 * f + l15 > mrow + r) S[f][r] = -1e30f;
    }
    // p = exp2(S'), per-lane row partials; P -> LDS (wave-private band)
#pragma unroll
    for (int f = 0; f < 4; ++f)
#pragma unroll
      for (int r = 0; r < 4; ++r) {
        float p = __builtin_amdgcn_exp2f(S[f][r]);
        l_lane[r] += p;
        Ps[16 * wave + quad * 4 + r][16 * f + l15] = f2bf(p);
      }
    // O += P @ V
#pragma unroll
    for (int kc = 0; kc < 2; ++kc) {
      bf16x8 ap = *(const bf16x8*)&Ps[16 * wave + l15][kc * 32 + quad * 8];
#pragma unroll
      for (int f = 0; f < 4; ++f)
        Of[f] = __builtin_amdgcn_mfma_f32_16x16x32_bf16(ap, vf[kc][f], Of[f], 0, 0, 0);
    }
  }

  // row-sum reduction across the 16 lanes sharing each row
#pragma unroll
  for (int d = 1; d < 16; d <<= 1)
#pragma unroll
    for (int r = 0; r < 4; ++r) l_lane[r] += __shfl_xor(l_lane[r], d);

#pragma unroll
  for (int f = 0; f < 4; ++f)
#pragma unroll
    for (int r = 0; r < 4; ++r) {
      int row = q0 + 16 * wave + quad * 4 + r;
      float o = Of[f][r] / l_lane[r];
      int col = h * DH + 16 * f + l15;
      concat[(size_t)(b * SEQ + row) * DM + col] = f2bf(o);
    }
}

// ---------- output projection, barrier-free: A rows + B frags in registers ----------
__global__ __launch_bounds__(256) void gemm_out(const unsigned short* __restrict__ A,
                                                const unsigned short* __restrict__ Bt,
                                                const float* __restrict__ bias,
                                                float* __restrict__ out) {
  const int m0 = blockIdx.x * 64;
  const int ng = blockIdx.y * 128;
  const int tid  = threadIdx.x;
  const int wave = tid >> 6, lane = tid & 63;
  const int l15  = lane & 15, quad = lane >> 4;

  bf16x8 afr[16];
  const unsigned short* arow = A + (size_t)(m0 + 16 * wave + l15) * DM;
#pragma unroll
  for (int k0i = 0; k0i < 8; ++k0i)
#pragma unroll
    for (int kc = 0; kc < 2; ++kc)
      afr[k0i * 2 + kc] = *(const bf16x8*)(arow + k0i * 64 + kc * 32 + quad * 8);

#pragma unroll 1
  for (int nt = 0; nt < 2; ++nt) {
    const int n0 = ng + nt * 64;
    f32x4 acc[4];
#pragma unroll
    for (int f = 0; f < 4; ++f) acc[f] = (f32x4){0.f, 0.f, 0.f, 0.f};
#pragma unroll
    for (int k0i = 0; k0i < 8; ++k0i) {
      bf16x8 bfv[2][4];
#pragma unroll
      for (int kc = 0; kc < 2; ++kc)
#pragma unroll
        for (int f = 0; f < 4; ++f)
          bfv[kc][f] = *(const bf16x8*)(Bt + (size_t)(n0 + 16 * f + l15) * DM + k0i * 64 + kc * 32 + quad * 8);
#pragma unroll
      for (int kc = 0; kc < 2; ++kc)
#pragma unroll
        for (int f = 0; f < 4; ++f)
          acc[f] = __builtin_amdgcn_mfma_f32_16x16x32_bf16(afr[k0i * 2 + kc], bfv[kc][f], acc[f], 0, 0, 0);
    }
#pragma unroll
    for (int f = 0; f < 4; ++f)
#pragma unroll
      for (int r = 0; r < 4; ++r) {
        int row = 16 * wave + quad * 4 + r;
        int col = 16 * f + l15;
        out[(size_t)(m0 + row) * DM + n0 + col] = acc[f][r] + bias[n0 + col];
      }
  }
}

extern "C" void kernel_launch(void* const* d_in, const int* in_sizes, int n_in,
                              void* d_out, int out_size, void* d_ws, size_t ws_size,
                              hipStream_t stream) {
  const float* query = (const float*)d_in[0];
  const float* key   = (const float*)d_in[1];
  const float* value = (const float*)d_in[2];
  const float* W_q   = (const float*)d_in[3];
  const float* b_q   = (const float*)d_in[4];
  const float* W_k   = (const float*)d_in[5];
  const float* b_k   = (const float*)d_in[6];
  const float* W_v   = (const float*)d_in[7];
  const float* b_v   = (const float*)d_in[8];
  const float* W_o   = (const float*)d_in[9];
  const float* b_o   = (const float*)d_in[10];
  float* out = (float*)d_out;

  char* ws = (char*)d_ws;
  unsigned short* Wqt    = (unsigned short*)(ws + 0);
  unsigned short* Wkt    = (unsigned short*)(ws + 524288);
  unsigned short* Wvt    = (unsigned short*)(ws + 1048576);
  unsigned short* Wot    = (unsigned short*)(ws + 1572864);
  unsigned short* Qp     = (unsigned short*)(ws + 2097152);
  unsigned short* Kp     = (unsigned short*)(ws + 10485760);
  unsigned short* Vpt    = (unsigned short*)(ws + 18874368);
  unsigned short* concat = (unsigned short*)(ws + 27262976);

  weight_prep<<<dim3(256), 256, 0, stream>>>(W_q, W_k, W_v, W_o, Wqt, Wkt, Wvt, Wot);

  proj128<<<dim3(64, 4, 3), 256, 0, stream>>>(query, key, value, Wqt, Wkt, Wvt,
                                              b_q, b_k, b_v, Qp, Kp, Vpt);

  attn_kernel<<<dim3(32, 32), 256, 0, stream>>>(Qp, Kp, Vpt, concat);

  gemm_out<<<dim3(128, 4), 256, 0, stream>>>(concat, Wot, b_o, out);
}

// Round 11
// 250.220 us; speedup vs baseline: 1.6045x; 1.6045x over previous
//
#include <hip/hip_runtime.h>
#include <hip/hip_bf16.h>

typedef __attribute__((ext_vector_type(8))) short bf16x8;
typedef __attribute__((ext_vector_type(4))) float f32x4;

#define SEQ 2048
#define DM  512
#define NH  8
#define DH  64
// (1/sqrt(2048)) * log2(e): folded into Q so scores come out ready for exp2
#define QSCALE 0.031879360f

__device__ __forceinline__ unsigned short f2bf(float f) {
  unsigned int u = __float_as_uint(f);
  unsigned int r = 0x7FFFu + ((u >> 16) & 1u);
  return (unsigned short)((u + r) >> 16);
}

__device__ __forceinline__ void load8f(const float* __restrict__ s,
                                       unsigned short* __restrict__ o) {
  float4 v0 = *(const float4*)s;
  float4 v1 = *(const float4*)(s + 4);
  o[0] = f2bf(v0.x); o[1] = f2bf(v0.y); o[2] = f2bf(v0.z); o[3] = f2bf(v0.w);
  o[4] = f2bf(v1.x); o[5] = f2bf(v1.y); o[6] = f2bf(v1.z); o[7] = f2bf(v1.w);
}

// ---------- fused weight prep: Wq/Wk/Wv per-head transpose + Wo transpose (f32->bf16) ----------
__global__ __launch_bounds__(256) void weight_prep(const float* __restrict__ Wq,
                                                   const float* __restrict__ Wk,
                                                   const float* __restrict__ Wv,
                                                   const float* __restrict__ Wo,
                                                   unsigned short* __restrict__ Wqt,
                                                   unsigned short* __restrict__ Wkt,
                                                   unsigned short* __restrict__ Wvt,
                                                   unsigned short* __restrict__ Wot) {
  const int which = blockIdx.x >> 6, wi = blockIdx.x & 63;
  const float* src;
  unsigned short* dst;
  int R, C, r0, c0;
  if (which < 3) {
    const float* W = (which == 0) ? Wq : (which == 1) ? Wk : Wv;
    unsigned short* D = (which == 0) ? Wqt : (which == 1) ? Wkt : Wvt;
    int h = wi >> 3;
    src = W + (size_t)h * 512 * 64;
    dst = D + (size_t)h * 64 * 512;
    R = 512; C = 64; r0 = (wi & 7) * 64; c0 = 0;
  } else {
    src = Wo; dst = Wot;
    R = 512; C = 512; r0 = (wi >> 3) * 64; c0 = (wi & 7) * 64;
  }
  __shared__ __align__(16) unsigned short T[64][72];
  const int tid = threadIdx.x;
#pragma unroll
  for (int i = 0; i < 2; ++i) {
    int c = tid + 256 * i;
    int lr = c >> 3, lc = (c & 7) * 8;
    __align__(16) unsigned short tmp[8];
    load8f(src + (size_t)(r0 + lr) * C + c0 + lc, tmp);
    *(uint4*)&T[lr][lc] = *(const uint4*)tmp;
  }
  __syncthreads();
#pragma unroll
  for (int i = 0; i < 2; ++i) {
    int c = tid + 256 * i;
    int orow = c >> 3, och = (c & 7) * 8;
    __align__(16) unsigned short tmp[8];
#pragma unroll
    for (int j = 0; j < 8; ++j) tmp[j] = T[och + j][orow];
    *(uint4*)(dst + (size_t)(c0 + orow) * R + r0 + och) = *(uint4*)tmp;
  }
}

// ---------- fused QKV projection v2: m-tile 64, n-tile 256, A read once ----------
// grid (128, 2, 3): x = m-tile, y = n-group (256), z = {Q,K,V}. 768 blocks = 3/CU.
__global__ __launch_bounds__(256, 3) void proj_v2(const float* __restrict__ q,
                                                  const float* __restrict__ k,
                                                  const float* __restrict__ v,
                                                  const unsigned short* __restrict__ Wqt,
                                                  const unsigned short* __restrict__ Wkt,
                                                  const unsigned short* __restrict__ Wvt,
                                                  const float* __restrict__ bq,
                                                  const float* __restrict__ bk,
                                                  const float* __restrict__ bv,
                                                  unsigned short* __restrict__ Qp,
                                                  unsigned short* __restrict__ Kp,
                                                  unsigned short* __restrict__ Vpt) {
  const int which = blockIdx.z;
  const float* X = (which == 0) ? q : (which == 1) ? k : v;
  const unsigned short* Wt = (which == 0) ? Wqt : (which == 1) ? Wkt : Wvt;
  const float* bias = (which == 0) ? bq : (which == 1) ? bk : bv;
  unsigned short* out = (which == 0) ? Qp : (which == 1) ? Kp : Vpt;
  const float ps = (which == 0) ? QSCALE : 1.0f;

  const int m0 = blockIdx.x * 64;
  const int n0 = blockIdx.y * 256;
  __shared__ __align__(16) unsigned short PS[64 * 72 + 256 * 72];  // As | Bs, 45 KB
  unsigned short (*As)[72] = (unsigned short (*)[72])PS;
  unsigned short (*Bs)[72] = (unsigned short (*)[72])(PS + 64 * 72);
  const int tid  = threadIdx.x;
  const int wave = tid >> 6, lane = tid & 63;
  const int l15  = lane & 15, quad = lane >> 4;
  const int cb   = wave * 64;  // each wave owns a 64-wide n-band, all 64 rows

  f32x4 acc[4][4];
#pragma unroll
  for (int i = 0; i < 4; ++i)
#pragma unroll
    for (int f = 0; f < 4; ++f) acc[i][f] = (f32x4){0.f, 0.f, 0.f, 0.f};

  for (int k0 = 0; k0 < DM; k0 += 64) {
    __syncthreads();
#pragma unroll
    for (int i = 0; i < 2; ++i) {  // A: 64x64 = 512 slots
      int c = tid + 256 * i;
      int lr = c >> 3, lc = (c & 7) * 8;
      __align__(16) unsigned short tmp[8];
      load8f(X + (size_t)(m0 + lr) * DM + k0 + lc, tmp);
      *(uint4*)&As[lr][lc] = *(const uint4*)tmp;
    }
#pragma unroll
    for (int i = 0; i < 8; ++i) {  // B: 256x64 = 2048 slots
      int c = tid + 256 * i;
      int lr = c >> 3, lc = (c & 7) * 8;
      *(uint4*)&Bs[lr][lc] = *(const uint4*)(Wt + (size_t)(n0 + lr) * DM + k0 + lc);
    }
    __syncthreads();
#pragma unroll
    for (int kc = 0; kc < 2; ++kc) {
      bf16x8 av[4], bv4[4];
#pragma unroll
      for (int i = 0; i < 4; ++i) av[i]  = *(const bf16x8*)&As[16 * i + l15][kc * 32 + quad * 8];
#pragma unroll
      for (int f = 0; f < 4; ++f) bv4[f] = *(const bf16x8*)&Bs[cb + 16 * f + l15][kc * 32 + quad * 8];
#pragma unroll
      for (int i = 0; i < 4; ++i)
#pragma unroll
        for (int f = 0; f < 4; ++f)
          acc[i][f] = __builtin_amdgcn_mfma_f32_16x16x32_bf16(av[i], bv4[f], acc[i][f], 0, 0, 0);
    }
  }

  const int b = m0 >> 11, sbase = m0 & (SEQ - 1);
  if (which < 2) {
#pragma unroll
    for (int i = 0; i < 4; ++i)
#pragma unroll
      for (int f = 0; f < 4; ++f)
#pragma unroll
        for (int r = 0; r < 4; ++r) {
          int s = sbase + 16 * i + quad * 4 + r;
          int col = n0 + cb + 16 * f + l15;
          int head = col >> 6, o = col & 63;
          float val = (acc[i][f][r] + bias[col]) * ps;
          out[(((size_t)(b * NH + head) * SEQ + s) << 6) + o] = f2bf(val);
        }
  } else {  // V: emit V^T [B,H,64,S] via wave-private LDS bounce
    __syncthreads();  // all waves done with As/Bs MFMA reads
    unsigned short* T = PS + wave * 4608;  // [64][72] per wave
#pragma unroll
    for (int i = 0; i < 4; ++i)
#pragma unroll
      for (int f = 0; f < 4; ++f)
#pragma unroll
        for (int r = 0; r < 4; ++r) {
          int lrow = 16 * i + quad * 4 + r;   // seq-local
          int lcol = 16 * f + l15;            // dh-local
          int col = n0 + cb + 16 * f + l15;
          T[lcol * 72 + lrow] = f2bf(acc[i][f][r] + bias[col]);
        }
    const int head = (n0 + cb) >> 6;
    unsigned short* dstb = out + ((size_t)(b * NH + head) * DH) * SEQ + sbase;
#pragma unroll
    for (int j = 0; j < 8; ++j) {
      int dh = (lane >> 3) + j * 8;
      int sc = (lane & 7) * 8;
      *(uint4*)(dstb + (size_t)dh * SEQ + sc) = *(const uint4*)&T[dh * 72 + sc];
    }
  }
}

// ---------- flash attention v5b: R7 LDS staging + paired q-tiles + depth-1 reg prefetch ----------
// grid (16 pair-slots, 32 bh); block handles qt = x then 31-x (uniform 33 chunks).
// V staging mapping FIXED: row = c>>3 (dh), col = (c&7)*8 (seq-local) — matches r7.
__global__ __launch_bounds__(256, 4) void attn_kernel(const unsigned short* __restrict__ Qp,
                                                      const unsigned short* __restrict__ Kp,
                                                      const unsigned short* __restrict__ Vpt,
                                                      unsigned short* __restrict__ concat) {
  const int xb = blockIdx.x;
  const int bh = blockIdx.y;
  const int b = bh >> 3, h = bh & 7;
  __shared__ __align__(16) unsigned short Ks[64][72], Vts[64][72], Ps[64][136];
  const int tid  = threadIdx.x;
  const int wave = tid >> 6, lane = tid & 63;
  const int l15  = lane & 15, quad = lane >> 4;
  const unsigned short* Qb = Qp  + (size_t)bh * SEQ * DH;
  const unsigned short* Kb = Kp  + (size_t)bh * SEQ * DH;
  const unsigned short* Vb = Vpt + (size_t)bh * DH * SEQ;

  const int c0 = tid, c1 = tid + 256;  // staging slot ids (8 elems each)
  const int r0s = c0 >> 3, r1s = c1 >> 3;        // rows 0..31 / 32..63
  const int o0s = (c0 & 7) * 8, o1s = (c1 & 7) * 8;

#pragma unroll 1
  for (int rep = 0; rep < 2; ++rep) {
    const int qt = rep ? (31 - xb) : xb;
    const int q0 = qt * 64;

    bf16x8 aq[2];
#pragma unroll
    for (int kc = 0; kc < 2; ++kc)
      aq[kc] = *(const bf16x8*)(Qb + (size_t)(q0 + 16 * wave + l15) * DH + kc * 32 + quad * 8);

    float l_lane[4];
    f32x4 Of[4];
#pragma unroll
    for (int r = 0; r < 4; ++r) l_lane[r] = 0.f;
#pragma unroll
    for (int f = 0; f < 4; ++f) Of[f] = (f32x4){0.f, 0.f, 0.f, 0.f};

    // prefetch chunk 0 into registers
    uint4 kreg[2], vreg[2];
    kreg[0] = *(const uint4*)(Kb + (size_t)r0s * DH + o0s);
    kreg[1] = *(const uint4*)(Kb + (size_t)r1s * DH + o1s);
    vreg[0] = *(const uint4*)(Vb + (size_t)r0s * SEQ + o0s);
    vreg[1] = *(const uint4*)(Vb + (size_t)r1s * SEQ + o1s);

#pragma unroll 1
    for (int ch = 0; ch <= qt; ++ch) {
      const int l0 = ch * 64;
      __syncthreads();  // prior chunk's LDS fragment reads complete
      *(uint4*)&Ks[r0s][o0s]  = kreg[0];
      *(uint4*)&Ks[r1s][o1s]  = kreg[1];
      *(uint4*)&Vts[r0s][o0s] = vreg[0];
      *(uint4*)&Vts[r1s][o1s] = vreg[1];
      if (ch < qt) {  // issue next chunk's loads: latency overlaps the compute below
        const int ln = l0 + 64;
        kreg[0] = *(const uint4*)(Kb + (size_t)(ln + r0s) * DH + o0s);
        kreg[1] = *(const uint4*)(Kb + (size_t)(ln + r1s) * DH + o1s);
        vreg[0] = *(const uint4*)(Vb + (size_t)r0s * SEQ + ln + o0s);
        vreg[1] = *(const uint4*)(Vb + (size_t)r1s * SEQ + ln + o1s);
      }
      __syncthreads();  // staging visible

      // S' = Q K^T (scale*log2e pre-folded into Q)
      f32x4 S[4];
#pragma unroll
      for (int f = 0; f < 4; ++f) S[f] = (f32x4){0.f, 0.f, 0.f, 0.f};
#pragma unroll
      for (int kc = 0; kc < 2; ++kc)
#pragma unroll
        for (int f = 0; f < 4; ++f) {
          bf16x8 bk = *(const bf16x8*)&Ks[16 * f + l15][kc * 32 + quad * 8];
          S[f] = __builtin_amdgcn_mfma_f32_16x16x32_bf16(aq[kc], bk, S[f], 0, 0, 0);
        }
      if (ch == qt) {  // diagonal tile: causal mask
        const int mrow = q0 + 16 * wave + quad * 4;
#pragma unroll
        for (int f = 0; f < 4; ++f)
#pragma unroll
          for (int r = 0; r < 4; ++r)
            if (l0 + 16 * f + l15 > mrow + r) S[f][r] = -1e30f;
      }
      // p = exp2(S'), per-lane row partials (reduced once at epilogue)
#pragma unroll
      for (int f = 0; f < 4; ++f)
#pragma unroll
        for (int r = 0; r < 4; ++r) {
          float p = __builtin_amdgcn_exp2f(S[f][r]);
          l_lane[r] += p;
          Ps[16 * wave + quad * 4 + r][16 * f + l15] = f2bf(p);  // wave-private rows
        }
      // O += P @ V
#pragma unroll
      for (int kc = 0; kc < 2; ++kc) {
        bf16x8 ap = *(const bf16x8*)&Ps[16 * wave + l15][kc * 32 + quad * 8];
#pragma unroll
        for (int f = 0; f < 4; ++f) {
          bf16x8 bv = *(const bf16x8*)&Vts[16 * f + l15][kc * 32 + quad * 8];
          Of[f] = __builtin_amdgcn_mfma_f32_16x16x32_bf16(ap, bv, Of[f], 0, 0, 0);
        }
      }
    }

    // row-sum reduction across the 16 lanes sharing each row
#pragma unroll
    for (int d = 1; d < 16; d <<= 1)
#pragma unroll
      for (int r = 0; r < 4; ++r) l_lane[r] += __shfl_xor(l_lane[r], d);

#pragma unroll
    for (int f = 0; f < 4; ++f)
#pragma unroll
      for (int r = 0; r < 4; ++r) {
        int row = q0 + 16 * wave + quad * 4 + r;
        float o = Of[f][r] / l_lane[r];
        int col = h * DH + 16 * f + l15;
        concat[(size_t)(b * SEQ + row) * DM + col] = f2bf(o);
      }
  }
}

// ---------- output projection, barrier-free: A rows + B frags in registers ----------
__global__ __launch_bounds__(256) void gemm_out(const unsigned short* __restrict__ A,
                                                const unsigned short* __restrict__ Bt,
                                                const float* __restrict__ bias,
                                                float* __restrict__ out) {
  const int m0 = blockIdx.x * 64;
  const int ng = blockIdx.y * 128;
  const int tid  = threadIdx.x;
  const int wave = tid >> 6, lane = tid & 63;
  const int l15  = lane & 15, quad = lane >> 4;

  bf16x8 afr[16];
  const unsigned short* arow = A + (size_t)(m0 + 16 * wave + l15) * DM;
#pragma unroll
  for (int k0i = 0; k0i < 8; ++k0i)
#pragma unroll
    for (int kc = 0; kc < 2; ++kc)
      afr[k0i * 2 + kc] = *(const bf16x8*)(arow + k0i * 64 + kc * 32 + quad * 8);

#pragma unroll 1
  for (int nt = 0; nt < 2; ++nt) {
    const int n0 = ng + nt * 64;
    f32x4 acc[4];
#pragma unroll
    for (int f = 0; f < 4; ++f) acc[f] = (f32x4){0.f, 0.f, 0.f, 0.f};
#pragma unroll
    for (int k0i = 0; k0i < 8; ++k0i) {
      bf16x8 bfv[2][4];
#pragma unroll
      for (int kc = 0; kc < 2; ++kc)
#pragma unroll
        for (int f = 0; f < 4; ++f)
          bfv[kc][f] = *(const bf16x8*)(Bt + (size_t)(n0 + 16 * f + l15) * DM + k0i * 64 + kc * 32 + quad * 8);
#pragma unroll
      for (int kc = 0; kc < 2; ++kc)
#pragma unroll
        for (int f = 0; f < 4; ++f)
          acc[f] = __builtin_amdgcn_mfma_f32_16x16x32_bf16(afr[k0i * 2 + kc], bfv[kc][f], acc[f], 0, 0, 0);
    }
#pragma unroll
    for (int f = 0; f < 4; ++f)
#pragma unroll
      for (int r = 0; r < 4; ++r) {
        int row = 16 * wave + quad * 4 + r;
        int col = 16 * f + l15;
        out[(size_t)(m0 + row) * DM + n0 + col] = acc[f][r] + bias[n0 + col];
      }
  }
}

extern "C" void kernel_launch(void* const* d_in, const int* in_sizes, int n_in,
                              void* d_out, int out_size, void* d_ws, size_t ws_size,
                              hipStream_t stream) {
  const float* query = (const float*)d_in[0];
  const float* key   = (const float*)d_in[1];
  const float* value = (const float*)d_in[2];
  const float* W_q   = (const float*)d_in[3];
  const float* b_q   = (const float*)d_in[4];
  const float* W_k   = (const float*)d_in[5];
  const float* b_k   = (const float*)d_in[6];
  const float* W_v   = (const float*)d_in[7];
  const float* b_v   = (const float*)d_in[8];
  const float* W_o   = (const float*)d_in[9];
  const float* b_o   = (const float*)d_in[10];
  float* out = (float*)d_out;

  char* ws = (char*)d_ws;
  unsigned short* Wqt    = (unsigned short*)(ws + 0);
  unsigned short* Wkt    = (unsigned short*)(ws + 524288);
  unsigned short* Wvt    = (unsigned short*)(ws + 1048576);
  unsigned short* Wot    = (unsigned short*)(ws + 1572864);
  unsigned short* Qp     = (unsigned short*)(ws + 2097152);
  unsigned short* Kp     = (unsigned short*)(ws + 10485760);
  unsigned short* Vpt    = (unsigned short*)(ws + 18874368);
  unsigned short* concat = (unsigned short*)(ws + 27262976);

  weight_prep<<<dim3(256), 256, 0, stream>>>(W_q, W_k, W_v, W_o, Wqt, Wkt, Wvt, Wot);

  proj_v2<<<dim3(128, 2, 3), 256, 0, stream>>>(query, key, value, Wqt, Wkt, Wvt,
                                               b_q, b_k, b_v, Qp, Kp, Vpt);

  attn_kernel<<<dim3(16, 32), 256, 0, stream>>>(Qp, Kp, Vpt, concat);

  gemm_out<<<dim3(128, 4), 256, 0, stream>>>(concat, Wot, b_o, out);
}